// Round 1
// baseline (229.119 us; speedup 1.0000x reference)
//
#include <hip/hip_runtime.h>
#include <hip/hip_bf16.h>
#include <math.h>

// Problem: out[b] = max_o( 2 * gelu_tanh( x[b,:] . weight[o,:] + bias[o] ) )
// B = IN_F = OUT_F = 4096, all fp32 inputs, fp32 output [4096].
//
// Strategy: fp32->bf16 convert into workspace, bf16 MFMA GEMM (m97-style
// 128x128 tile, 16x16x32 MFMA, global_load_lds width 16), fused
// bias+gelu+scale+rowmax epilogue writing per-tile partial maxes, then a
// small reduce kernel.
//
// Workspace layout (needs 64.5 MB):
//   xb       : 4096*4096 bf16 (32 MB)
//   wb       : 4096*4096 bf16 (32 MB)
//   partials : 32 * 4096 f32  (512 KB)

typedef unsigned short u16;
typedef short bf16x8 __attribute__((ext_vector_type(8)));   // 8 bf16 = 4 VGPRs
typedef float f32x4 __attribute__((ext_vector_type(4)));
typedef unsigned short ushort8 __attribute__((ext_vector_type(8)));

#define MDIM 4096
#define NDIM 4096
#define KD   4096
#define BM 128
#define BN 128
#define BK 32
#define NTN (NDIM / BN)   // 32 column tiles

__device__ __forceinline__ u16 f2bf(float f) {
  // round-to-nearest-even bf16 (inputs are finite; no NaN handling needed)
  unsigned int u = __float_as_uint(f);
  u += 0x7fffu + ((u >> 16) & 1u);
  return (u16)(u >> 16);
}

__global__ void f32_to_bf16_kernel(const float* __restrict__ in,
                                   u16* __restrict__ out, int n8) {
  int i = blockIdx.x * blockDim.x + threadIdx.x;
  int stride = gridDim.x * blockDim.x;
  for (; i < n8; i += stride) {
    const float4* p = (const float4*)in + (size_t)i * 2;
    float4 a = p[0];
    float4 b = p[1];
    ushort8 o;
    o[0] = f2bf(a.x); o[1] = f2bf(a.y); o[2] = f2bf(a.z); o[3] = f2bf(a.w);
    o[4] = f2bf(b.x); o[5] = f2bf(b.y); o[6] = f2bf(b.z); o[7] = f2bf(b.w);
    ((ushort8*)out)[i] = o;
  }
}

__device__ __forceinline__ void gload_lds16(const void* g, void* l) {
  // async global->LDS, 16B per lane; LDS dest is wave-uniform base + lane*16
  __builtin_amdgcn_global_load_lds(
      (__attribute__((address_space(1))) void*)(g),
      (__attribute__((address_space(3))) void*)(l), 16, 0, 0);
}

__global__ __launch_bounds__(256) void gemm_gelu_max_kernel(
    const u16* __restrict__ A,   // x as bf16, [4096][4096] row-major (K contig)
    const u16* __restrict__ Bw,  // weight as bf16, [4096][4096] (N-major, K contig)
    const float* __restrict__ bias,
    float* __restrict__ partials) {
  __shared__ u16 As[BM * BK];   // [row][k], 8 KB
  __shared__ u16 Bs[BN * BK];   // [col][k], 8 KB
  __shared__ float pm[2][BM];

  const int t = threadIdx.x;
  const int wave = t >> 6;
  const int lane = t & 63;
  const int wr = wave >> 1;     // wave row in 2x2 grid
  const int wc = wave & 1;      // wave col
  const int l15 = lane & 15;
  const int l4 = lane >> 4;
  const int brow = blockIdx.y * BM;
  const int bcol = blockIdx.x * BN;

  f32x4 acc[4][4] = {};  // wave computes 64x64 = 4x4 fragments of 16x16

  for (int k0 = 0; k0 < KD; k0 += BK) {
    // --- stage A-tile and B-tile (each 128x32 bf16 = 8 KB = 512 x 16B chunks)
#pragma unroll
    for (int i = 0; i < 2; ++i) {
      int chunk = i * 256 + t;          // 0..511
      int row = chunk >> 2;             // 4 chunks (64B) per row
      int kk = (chunk & 3) * 8;
      // wave-uniform LDS base (lane offset lane*16B applied by HW)
      u16* lbase_a = As + (size_t)(i * 256 + wave * 64) * 8;
      u16* lbase_b = Bs + (size_t)(i * 256 + wave * 64) * 8;
      gload_lds16(A + (size_t)(brow + row) * KD + k0 + kk, lbase_a);
      gload_lds16(Bw + (size_t)(bcol + row) * KD + k0 + kk, lbase_b);
    }
    __syncthreads();  // compiler drains vmcnt before barrier

    // --- LDS -> fragments. A-frag: row=lane&15, k=(lane>>4)*8+j
    bf16x8 af[4], bf[4];
#pragma unroll
    for (int m = 0; m < 4; ++m)
      af[m] = *(const bf16x8*)&As[(size_t)(wr * 64 + m * 16 + l15) * BK + l4 * 8];
#pragma unroll
    for (int n = 0; n < 4; ++n)
      bf[n] = *(const bf16x8*)&Bs[(size_t)(wc * 64 + n * 16 + l15) * BK + l4 * 8];

#pragma unroll
    for (int m = 0; m < 4; ++m)
#pragma unroll
      for (int n = 0; n < 4; ++n)
        acc[m][n] = __builtin_amdgcn_mfma_f32_16x16x32_bf16(af[m], bf[n], acc[m][n], 0, 0, 0);

    __syncthreads();
  }

  // --- epilogue: bias + gelu_tanh*2, then row-max.
  // C/D layout: col = lane&15, row = (lane>>4)*4 + j  [guide m89]
  float rmax_[4][4];
#pragma unroll
  for (int m = 0; m < 4; ++m)
#pragma unroll
    for (int j = 0; j < 4; ++j) rmax_[m][j] = -1e30f;

#pragma unroll
  for (int n = 0; n < 4; ++n) {
    const float bv = bias[bcol + wc * 64 + n * 16 + l15];
#pragma unroll
    for (int m = 0; m < 4; ++m) {
#pragma unroll
      for (int j = 0; j < 4; ++j) {
        float x = acc[m][n][j] + bv;
        // 2*gelu_tanh(x) = x * (1 + tanh(u)),  u = K*(x + C*x^3)
        // tanh(u) = 1 - 2/(exp2(2u*log2e)+1)
        float u = 0.7978845608f * x * (1.0f + 0.044715f * x * x);
        float e = exp2f(u * 2.8853900817779268f);  // 2*log2(e)
        float r = __builtin_amdgcn_rcpf(e + 1.0f);
        float g = 2.0f * x * (1.0f - r);
        rmax_[m][j] = fmaxf(rmax_[m][j], g);
      }
    }
  }

  // butterfly max across the 16 column-lanes (low 4 lane bits)
#pragma unroll
  for (int m = 0; m < 4; ++m) {
#pragma unroll
    for (int j = 0; j < 4; ++j) {
      float v = rmax_[m][j];
      v = fmaxf(v, __shfl_xor(v, 1, 64));
      v = fmaxf(v, __shfl_xor(v, 2, 64));
      v = fmaxf(v, __shfl_xor(v, 4, 64));
      v = fmaxf(v, __shfl_xor(v, 8, 64));
      if (l15 == 0) pm[wc][wr * 64 + m * 16 + l4 * 4 + j] = v;
    }
  }
  __syncthreads();

  if (t < BM) {
    float v = fmaxf(pm[0][t], pm[1][t]);
    partials[(size_t)blockIdx.x * MDIM + brow + t] = v;
  }
}

__global__ void rowmax_kernel(const float* __restrict__ partials,
                              float* __restrict__ out) {
  int r = blockIdx.x * blockDim.x + threadIdx.x;
  if (r < MDIM) {
    float m = -1e30f;
#pragma unroll 8
    for (int tt = 0; tt < NTN; ++tt) m = fmaxf(m, partials[(size_t)tt * MDIM + r]);
    out[r] = m;
  }
}

extern "C" void kernel_launch(void* const* d_in, const int* in_sizes, int n_in,
                              void* d_out, int out_size, void* d_ws, size_t ws_size,
                              hipStream_t stream) {
  const float* x = (const float*)d_in[0];
  const float* w = (const float*)d_in[1];
  const float* bias = (const float*)d_in[2];
  // d_in[3] = pool_kernel_size (mathematical no-op in the reference)
  float* out = (float*)d_out;

  u16* xb = (u16*)d_ws;
  u16* wb = xb + (size_t)MDIM * KD;
  float* partials = (float*)(wb + (size_t)NDIM * KD);

  const int n8 = (MDIM * KD) / 8;
  f32_to_bf16_kernel<<<2048, 256, 0, stream>>>(x, xb, n8);
  f32_to_bf16_kernel<<<2048, 256, 0, stream>>>(w, wb, n8);

  dim3 grid(NDIM / BN, MDIM / BM);
  gemm_gelu_max_kernel<<<grid, 256, 0, stream>>>(xb, wb, bias, partials);

  rowmax_kernel<<<MDIM / 256, 256, 0, stream>>>(partials, out);
}

// Round 2
// 188.064 us; speedup vs baseline: 1.2183x; 1.2183x over previous
//
#include <hip/hip_runtime.h>
#include <hip/hip_bf16.h>
#include <math.h>

// out[b] = max_o( 2 * gelu_tanh( x[b,:] . weight[o,:] + bias[o] ) )
// 4096 x 4096 x 4096, fp32 in, fp32 out[4096].
//
// Round 2: 256x256-tile 8-wave bf16 MFMA GEMM (8-phase-class schedule):
//   - BK=64, double-buffered 128 KiB LDS, 1 block/CU, grid 16x16
//   - T2: XOR swizzle (row&7)<<4 via pre-swizzled global src + swizzled ds_read
//   - T3/T4: per-K-tile: stage whole next tile (8 gload_lds/thread), counted
//     s_waitcnt vmcnt(8) (never 0 in main loop), 4 phases x 16 MFMA with raw
//     s_barrier pairs
//   - T5: s_setprio(1) around MFMA clusters
// Epilogue fuses bias + 2*gelu_tanh + row-max -> partials, then reduce kernel.

typedef unsigned short u16;
typedef short bf16x8 __attribute__((ext_vector_type(8)));   // 8 bf16 = 4 VGPRs
typedef float f32x4 __attribute__((ext_vector_type(4)));
typedef unsigned short ushort8 __attribute__((ext_vector_type(8)));

#define MDIM 4096
#define NDIM 4096
#define KD   4096
#define BM 256
#define BN 256
#define BK 64
#define NKT (KD / BK)          // 64 K-tiles
#define NTN (NDIM / BN)        // 16 column tiles
#define HT  (128 * 64)         // u16 elements per half-tile (16 KB)

__device__ __forceinline__ u16 f2bf(float f) {
  unsigned int u = __float_as_uint(f);
  u += 0x7fffu + ((u >> 16) & 1u);
  return (u16)(u >> 16);
}

__global__ void f32_to_bf16_kernel(const float* __restrict__ in,
                                   u16* __restrict__ out, int n8) {
  int i = blockIdx.x * blockDim.x + threadIdx.x;
  int stride = gridDim.x * blockDim.x;
  for (; i < n8; i += stride) {
    const float4* p = (const float4*)in + (size_t)i * 2;
    float4 a = p[0];
    float4 b = p[1];
    ushort8 o;
    o[0] = f2bf(a.x); o[1] = f2bf(a.y); o[2] = f2bf(a.z); o[3] = f2bf(a.w);
    o[4] = f2bf(b.x); o[5] = f2bf(b.y); o[6] = f2bf(b.z); o[7] = f2bf(b.w);
    ((ushort8*)out)[i] = o;
  }
}

__device__ __forceinline__ void gload_lds16(const u16* g, u16* l) {
  __builtin_amdgcn_global_load_lds(
      (__attribute__((address_space(1))) void*)(g),
      (__attribute__((address_space(3))) void*)(l), 16, 0, 0);
}

// Stage one 128x64 bf16 half-tile: 1024 16B chunks, 2 per thread.
// LDS dest is linear; global source is pre-swizzled so that LDS linear
// position (row, c16) holds logical k-chunk (c16 ^ (row&7)).  (rule #21)
__device__ __forceinline__ void stage_half(const u16* __restrict__ src,
                                           u16* dst, int t, int wave) {
#pragma unroll
  for (int it = 0; it < 2; ++it) {
    int chunk = it * 512 + t;
    int row = chunk >> 3;
    int c16 = chunk & 7;
    gload_lds16(src + (size_t)row * KD + ((c16 ^ (row & 7)) << 3),
                dst + ((it * 512 + wave * 64) << 3));
  }
}

// Swizzled fragment read: logical (row r, k-slice ks) -> bf16x8.
// Byte addr = r*128 + ((ks*4 + l4) ^ (r&7)) * 16 ; here r&7 == l15&7 == l7.
__device__ __forceinline__ bf16x8 frag(const u16* half_, int r, int ks,
                                       int l4, int l7) {
  int c16 = ((ks << 2) + l4) ^ l7;
  return *(const bf16x8*)(half_ + r * 64 + (c16 << 3));
}

#define LDSOFF(buf, arr, half) ((((((buf) * 2) + (arr)) * 2) + (half)) * HT)

__global__ __launch_bounds__(512, 2) void gemm_gelu_max_kernel(
    const u16* __restrict__ A,    // x bf16 [4096][4096], K contiguous
    const u16* __restrict__ Bw,   // weight bf16 [4096][4096], K contiguous
    const float* __restrict__ bias,
    float* __restrict__ partials) {
  __shared__ __align__(16) u16 sm[2 * 2 * 2 * HT];  // 128 KiB
  __shared__ float pmx[8][128];                      // 4 KiB

  const int t = threadIdx.x;
  const int wave = t >> 6;
  const int lane = t & 63;
  const int warp_m = wave >> 2;        // 0..1 -> A half
  const int warp_n = wave & 3;         // 0..3
  const int wn2 = warp_n >> 1;         // B half
  const int bn0 = (warp_n & 1) * 64;   // col base within B half
  const int l15 = lane & 15;
  const int l4 = lane >> 4;
  const int l7 = lane & 7;
  const int brow = blockIdx.y * BM;
  const int bcol = blockIdx.x * BN;

  f32x4 acc[8][4] = {};   // per-wave 128x64 output: 8 m-frags x 4 n-frags

  // ---- prologue: stage K-tile 0 into buf 0 (8 issues/thread)
  stage_half(A  + (size_t)(brow)*KD,        sm + LDSOFF(0, 0, 0), t, wave);
  stage_half(A  + (size_t)(brow + 128)*KD,  sm + LDSOFF(0, 0, 1), t, wave);
  stage_half(Bw + (size_t)(bcol)*KD,        sm + LDSOFF(0, 1, 0), t, wave);
  stage_half(Bw + (size_t)(bcol + 128)*KD,  sm + LDSOFF(0, 1, 1), t, wave);

  for (int kt = 0; kt < NKT; ++kt) {
    const int c = kt & 1;
    const u16* Ah = sm + LDSOFF(c, 0, warp_m);
    const u16* Bh = sm + LDSOFF(c, 1, wn2);
    bf16x8 bfr[4][2];
    bf16x8 af[2][2];

#pragma unroll
    for (int p = 0; p < 4; ++p) {
      if (p == 0) {
        // stage whole next K-tile into the other buffer, then counted wait
        if (kt + 1 < NKT) {
          const int k0 = (kt + 1) * BK;
          const int b = c ^ 1;
          stage_half(A  + (size_t)(brow)*KD + k0,       sm + LDSOFF(b, 0, 0), t, wave);
          stage_half(A  + (size_t)(brow + 128)*KD + k0, sm + LDSOFF(b, 0, 1), t, wave);
          stage_half(Bw + (size_t)(bcol)*KD + k0,       sm + LDSOFF(b, 1, 0), t, wave);
          stage_half(Bw + (size_t)(bcol + 128)*KD + k0, sm + LDSOFF(b, 1, 1), t, wave);
          asm volatile("s_waitcnt vmcnt(8)" ::: "memory");
        } else {
          asm volatile("s_waitcnt vmcnt(0)" ::: "memory");
        }
        __builtin_amdgcn_s_barrier();
        // B fragments for the whole K-tile (register-resident all 4 phases)
#pragma unroll
        for (int n = 0; n < 4; ++n)
#pragma unroll
          for (int ks = 0; ks < 2; ++ks)
            bfr[n][ks] = frag(Bh, bn0 + n * 16 + l15, ks, l4, l7);
      }
      // A fragments for this phase's m-group
#pragma unroll
      for (int mm = 0; mm < 2; ++mm)
#pragma unroll
        for (int ks = 0; ks < 2; ++ks)
          af[mm][ks] = frag(Ah, (p * 2 + mm) * 16 + l15, ks, l4, l7);

      __builtin_amdgcn_s_barrier();
      __builtin_amdgcn_s_setprio(1);
#pragma unroll
      for (int mm = 0; mm < 2; ++mm)
#pragma unroll
        for (int n = 0; n < 4; ++n)
#pragma unroll
          for (int ks = 0; ks < 2; ++ks)
            acc[p * 2 + mm][n] = __builtin_amdgcn_mfma_f32_16x16x32_bf16(
                af[mm][ks], bfr[n][ks], acc[p * 2 + mm][n], 0, 0, 0);
      __builtin_amdgcn_s_setprio(0);
      __builtin_amdgcn_s_barrier();
    }
  }

  // ---- epilogue: bias + 2*gelu_tanh, row-max over cols
  // C/D layout per 16x16 frag: col = l15, row = l4*4 + j
  float rmax_[8][4];
#pragma unroll
  for (int m = 0; m < 8; ++m)
#pragma unroll
    for (int j = 0; j < 4; ++j) rmax_[m][j] = -1e30f;

#pragma unroll
  for (int n = 0; n < 4; ++n) {
    const float bv = bias[bcol + warp_n * 64 + n * 16 + l15];
#pragma unroll
    for (int m = 0; m < 8; ++m) {
#pragma unroll
      for (int j = 0; j < 4; ++j) {
        float x = acc[m][n][j] + bv;
        float u = 0.7978845608f * x * (1.0f + 0.044715f * x * x);
        float e = exp2f(u * 2.8853900817779268f);   // 2*log2(e)
        float r = __builtin_amdgcn_rcpf(e + 1.0f);
        float g = 2.0f * x * (1.0f - r);
        rmax_[m][j] = fmaxf(rmax_[m][j], g);
      }
    }
  }

  // butterfly max across the 16 column-lanes
#pragma unroll
  for (int m = 0; m < 8; ++m) {
#pragma unroll
    for (int j = 0; j < 4; ++j) {
      float v = rmax_[m][j];
      v = fmaxf(v, __shfl_xor(v, 1, 64));
      v = fmaxf(v, __shfl_xor(v, 2, 64));
      v = fmaxf(v, __shfl_xor(v, 4, 64));
      v = fmaxf(v, __shfl_xor(v, 8, 64));
      if (l15 == 0) pmx[wave][m * 16 + l4 * 4 + j] = v;
    }
  }
  __syncthreads();

  if (t < 256) {
    int gm = t >> 7;             // which warp_m row-half
    int r = t & 127;
    float v = fmaxf(fmaxf(pmx[gm * 4 + 0][r], pmx[gm * 4 + 1][r]),
                    fmaxf(pmx[gm * 4 + 2][r], pmx[gm * 4 + 3][r]));
    partials[(size_t)blockIdx.x * MDIM + brow + t] = v;
  }
}

__global__ void rowmax_kernel(const float* __restrict__ partials,
                              float* __restrict__ out) {
  int r = blockIdx.x * blockDim.x + threadIdx.x;
  if (r < MDIM) {
    float m = -1e30f;
#pragma unroll
    for (int tt = 0; tt < NTN; ++tt) m = fmaxf(m, partials[(size_t)tt * MDIM + r]);
    out[r] = m;
  }
}

extern "C" void kernel_launch(void* const* d_in, const int* in_sizes, int n_in,
                              void* d_out, int out_size, void* d_ws, size_t ws_size,
                              hipStream_t stream) {
  const float* x = (const float*)d_in[0];
  const float* w = (const float*)d_in[1];
  const float* bias = (const float*)d_in[2];
  float* out = (float*)d_out;

  u16* xb = (u16*)d_ws;
  u16* wb = xb + (size_t)MDIM * KD;
  float* partials = (float*)(wb + (size_t)NDIM * KD);

  const int n8 = (MDIM * KD) / 8;
  f32_to_bf16_kernel<<<2048, 256, 0, stream>>>(x, xb, n8);
  f32_to_bf16_kernel<<<2048, 256, 0, stream>>>(w, wb, n8);

  dim3 grid(NDIM / BN, MDIM / BM);   // 16 x 16 = 256 blocks, 1 per CU
  gemm_gelu_max_kernel<<<grid, 512, 0, stream>>>(xb, wb, bias, partials);

  rowmax_kernel<<<MDIM / 256, 256, 0, stream>>>(partials, out);
}

// Round 3
// 181.724 us; speedup vs baseline: 1.2608x; 1.0349x over previous
//
#include <hip/hip_runtime.h>
#include <hip/hip_bf16.h>
#include <math.h>

// out[b] = max_o( 2 * gelu_tanh( x[b,:] . weight[o,:] + bias[o] ) )
// 4096 x 4096 x 4096, fp32 in, fp32 out[4096].
//
// Round 3: round-2 256x256 schedule + T1 XCD-aware 2D block swizzle.
// Theory: round-2 is L2-miss / L3-BW bound (12.7 TB/s staged, 2.3x HBM
// over-fetch). Consecutive blockIdx round-robins over the 8 XCDs, so each
// XCD's 32 resident blocks touch ~64 MB of panels (>> 4 MiB L2). Remap so
// XCD c owns a 4x8 tile region: per-K-step active set = 8 A-tiles + 4
// B-tiles = 768 KB -> L2-resident, L3 traffic cut ~5x.
//   bid = c + 8*j (HW: bid%8 -> XCD c). Region origin (cx,cy) =
//   ((c&3)*4, (c>>2)*8); block offset (j&3, j>>2). Bijective on 16x16.

typedef unsigned short u16;
typedef short bf16x8 __attribute__((ext_vector_type(8)));   // 8 bf16 = 4 VGPRs
typedef float f32x4 __attribute__((ext_vector_type(4)));
typedef unsigned short ushort8 __attribute__((ext_vector_type(8)));

#define MDIM 4096
#define NDIM 4096
#define KD   4096
#define BM 256
#define BN 256
#define BK 64
#define NKT (KD / BK)          // 64 K-tiles
#define NTN (NDIM / BN)        // 16 column tiles
#define HT  (128 * 64)         // u16 elements per half-tile (16 KB)

__device__ __forceinline__ u16 f2bf(float f) {
  unsigned int u = __float_as_uint(f);
  u += 0x7fffu + ((u >> 16) & 1u);
  return (u16)(u >> 16);
}

__global__ void f32_to_bf16_kernel(const float* __restrict__ in,
                                   u16* __restrict__ out, int n8) {
  int i = blockIdx.x * blockDim.x + threadIdx.x;
  int stride = gridDim.x * blockDim.x;
  for (; i < n8; i += stride) {
    const float4* p = (const float4*)in + (size_t)i * 2;
    float4 a = p[0];
    float4 b = p[1];
    ushort8 o;
    o[0] = f2bf(a.x); o[1] = f2bf(a.y); o[2] = f2bf(a.z); o[3] = f2bf(a.w);
    o[4] = f2bf(b.x); o[5] = f2bf(b.y); o[6] = f2bf(b.z); o[7] = f2bf(b.w);
    ((ushort8*)out)[i] = o;
  }
}

__device__ __forceinline__ void gload_lds16(const u16* g, u16* l) {
  __builtin_amdgcn_global_load_lds(
      (__attribute__((address_space(1))) void*)(g),
      (__attribute__((address_space(3))) void*)(l), 16, 0, 0);
}

// Stage one 128x64 bf16 half-tile: 1024 16B chunks, 2 per thread.
// LDS dest linear; global src pre-swizzled: LDS (row, c16) holds logical
// k-chunk (c16 ^ (row&7)).  (rule #21: same involution on read side)
__device__ __forceinline__ void stage_half(const u16* __restrict__ src,
                                           u16* dst, int t, int wave) {
#pragma unroll
  for (int it = 0; it < 2; ++it) {
    int chunk = it * 512 + t;
    int row = chunk >> 3;
    int c16 = chunk & 7;
    gload_lds16(src + (size_t)row * KD + ((c16 ^ (row & 7)) << 3),
                dst + ((it * 512 + wave * 64) << 3));
  }
}

// Swizzled fragment read: logical (row r, k-slice ks) -> bf16x8.
__device__ __forceinline__ bf16x8 frag(const u16* half_, int r, int ks,
                                       int l4, int l7) {
  int c16 = ((ks << 2) + l4) ^ l7;
  return *(const bf16x8*)(half_ + r * 64 + (c16 << 3));
}

#define LDSOFF(buf, arr, half) ((((((buf) * 2) + (arr)) * 2) + (half)) * HT)

__global__ __launch_bounds__(512, 2) void gemm_gelu_max_kernel(
    const u16* __restrict__ A,    // x bf16 [4096][4096], K contiguous
    const u16* __restrict__ Bw,   // weight bf16 [4096][4096], K contiguous
    const float* __restrict__ bias,
    float* __restrict__ partials) {
  __shared__ __align__(16) u16 sm[2 * 2 * 2 * HT];  // 128 KiB
  __shared__ float pmx[8][128];                      // 4 KiB

  const int t = threadIdx.x;
  const int wave = t >> 6;
  const int lane = t & 63;
  const int warp_m = wave >> 2;        // 0..1 -> A half
  const int warp_n = wave & 3;         // 0..3
  const int wn2 = warp_n >> 1;         // B half
  const int bn0 = (warp_n & 1) * 64;   // col base within B half
  const int l15 = lane & 15;
  const int l4 = lane >> 4;
  const int l7 = lane & 7;

  // T1: XCD-aware 2D swizzle. bid%8 = XCD; XCD c owns a 4(x) x 8(y) region.
  const int bid = blockIdx.x;
  const int c8 = bid & 7;
  const int j = bid >> 3;
  const int tx = ((c8 & 3) << 2) + (j & 3);    // 0..15
  const int ty = ((c8 >> 2) << 3) + (j >> 2);  // 0..15
  const int brow = ty * BM;
  const int bcol = tx * BN;

  f32x4 acc[8][4] = {};   // per-wave 128x64 output: 8 m-frags x 4 n-frags

  // ---- prologue: stage K-tile 0 into buf 0 (8 issues/thread)
  stage_half(A  + (size_t)(brow)*KD,        sm + LDSOFF(0, 0, 0), t, wave);
  stage_half(A  + (size_t)(brow + 128)*KD,  sm + LDSOFF(0, 0, 1), t, wave);
  stage_half(Bw + (size_t)(bcol)*KD,        sm + LDSOFF(0, 1, 0), t, wave);
  stage_half(Bw + (size_t)(bcol + 128)*KD,  sm + LDSOFF(0, 1, 1), t, wave);

  for (int kt = 0; kt < NKT; ++kt) {
    const int c = kt & 1;
    const u16* Ah = sm + LDSOFF(c, 0, warp_m);
    const u16* Bh = sm + LDSOFF(c, 1, wn2);
    bf16x8 bfr[4][2];
    bf16x8 af[2][2];

#pragma unroll
    for (int p = 0; p < 4; ++p) {
      if (p == 0) {
        // stage whole next K-tile into the other buffer, then counted wait
        if (kt + 1 < NKT) {
          const int k0 = (kt + 1) * BK;
          const int b = c ^ 1;
          stage_half(A  + (size_t)(brow)*KD + k0,       sm + LDSOFF(b, 0, 0), t, wave);
          stage_half(A  + (size_t)(brow + 128)*KD + k0, sm + LDSOFF(b, 0, 1), t, wave);
          stage_half(Bw + (size_t)(bcol)*KD + k0,       sm + LDSOFF(b, 1, 0), t, wave);
          stage_half(Bw + (size_t)(bcol + 128)*KD + k0, sm + LDSOFF(b, 1, 1), t, wave);
          asm volatile("s_waitcnt vmcnt(8)" ::: "memory");
        } else {
          asm volatile("s_waitcnt vmcnt(0)" ::: "memory");
        }
        __builtin_amdgcn_s_barrier();
        // B fragments for the whole K-tile (register-resident all 4 phases)
#pragma unroll
        for (int n = 0; n < 4; ++n)
#pragma unroll
          for (int ks = 0; ks < 2; ++ks)
            bfr[n][ks] = frag(Bh, bn0 + n * 16 + l15, ks, l4, l7);
      }
      // A fragments for this phase's m-group
#pragma unroll
      for (int mm = 0; mm < 2; ++mm)
#pragma unroll
        for (int ks = 0; ks < 2; ++ks)
          af[mm][ks] = frag(Ah, (p * 2 + mm) * 16 + l15, ks, l4, l7);

      __builtin_amdgcn_s_barrier();
      __builtin_amdgcn_s_setprio(1);
#pragma unroll
      for (int mm = 0; mm < 2; ++mm)
#pragma unroll
        for (int n = 0; n < 4; ++n)
#pragma unroll
          for (int ks = 0; ks < 2; ++ks)
            acc[p * 2 + mm][n] = __builtin_amdgcn_mfma_f32_16x16x32_bf16(
                af[mm][ks], bfr[n][ks], acc[p * 2 + mm][n], 0, 0, 0);
      __builtin_amdgcn_s_setprio(0);
      __builtin_amdgcn_s_barrier();
    }
  }

  // ---- epilogue: bias + 2*gelu_tanh, row-max over cols
  // C/D layout per 16x16 frag: col = l15, row = l4*4 + j
  float rmax_[8][4];
#pragma unroll
  for (int m = 0; m < 8; ++m)
#pragma unroll
    for (int j2 = 0; j2 < 4; ++j2) rmax_[m][j2] = -1e30f;

#pragma unroll
  for (int n = 0; n < 4; ++n) {
    const float bv = bias[bcol + warp_n * 64 + n * 16 + l15];
#pragma unroll
    for (int m = 0; m < 8; ++m) {
#pragma unroll
      for (int j2 = 0; j2 < 4; ++j2) {
        float x = acc[m][n][j2] + bv;
        float u = 0.7978845608f * x * (1.0f + 0.044715f * x * x);
        float e = exp2f(u * 2.8853900817779268f);   // 2*log2(e)
        float r = __builtin_amdgcn_rcpf(e + 1.0f);
        float g = 2.0f * x * (1.0f - r);
        rmax_[m][j2] = fmaxf(rmax_[m][j2], g);
      }
    }
  }

  // butterfly max across the 16 column-lanes
#pragma unroll
  for (int m = 0; m < 8; ++m) {
#pragma unroll
    for (int j2 = 0; j2 < 4; ++j2) {
      float v = rmax_[m][j2];
      v = fmaxf(v, __shfl_xor(v, 1, 64));
      v = fmaxf(v, __shfl_xor(v, 2, 64));
      v = fmaxf(v, __shfl_xor(v, 4, 64));
      v = fmaxf(v, __shfl_xor(v, 8, 64));
      if (l15 == 0) pmx[wave][m * 16 + l4 * 4 + j2] = v;
    }
  }
  __syncthreads();

  if (t < 256) {
    int gm = t >> 7;             // which warp_m row-half
    int r = t & 127;
    float v = fmaxf(fmaxf(pmx[gm * 4 + 0][r], pmx[gm * 4 + 1][r]),
                    fmaxf(pmx[gm * 4 + 2][r], pmx[gm * 4 + 3][r]));
    partials[(size_t)tx * MDIM + brow + t] = v;
  }
}

__global__ void rowmax_kernel(const float* __restrict__ partials,
                              float* __restrict__ out) {
  int r = blockIdx.x * blockDim.x + threadIdx.x;
  if (r < MDIM) {
    float m = -1e30f;
#pragma unroll
    for (int tt = 0; tt < NTN; ++tt) m = fmaxf(m, partials[(size_t)tt * MDIM + r]);
    out[r] = m;
  }
}

extern "C" void kernel_launch(void* const* d_in, const int* in_sizes, int n_in,
                              void* d_out, int out_size, void* d_ws, size_t ws_size,
                              hipStream_t stream) {
  const float* x = (const float*)d_in[0];
  const float* w = (const float*)d_in[1];
  const float* bias = (const float*)d_in[2];
  float* out = (float*)d_out;

  u16* xb = (u16*)d_ws;
  u16* wb = xb + (size_t)MDIM * KD;
  float* partials = (float*)(wb + (size_t)NDIM * KD);

  const int n8 = (MDIM * KD) / 8;
  f32_to_bf16_kernel<<<2048, 256, 0, stream>>>(x, xb, n8);
  f32_to_bf16_kernel<<<2048, 256, 0, stream>>>(w, wb, n8);

  gemm_gelu_max_kernel<<<dim3(256), 512, 0, stream>>>(xb, wb, bias, partials);

  rowmax_kernel<<<MDIM / 256, 256, 0, stream>>>(partials, out);
}

// Round 4
// 169.271 us; speedup vs baseline: 1.3536x; 1.0736x over previous
//
#include <hip/hip_runtime.h>
#include <hip/hip_bf16.h>
#include <math.h>

// out[b] = max_o( 2 * gelu_tanh( x[b,:] . weight[o,:] + bias[o] ) )
// 4096 x 4096 x 4096, fp32 in, fp32 out[4096].
//
// Round 4: round-3 structure (256x256, BK=64, 8 waves, T1 XCD swizzle,
// T2 LDS XOR swizzle, counted vmcnt, 2-barrier phases, setprio) +
// address-precompute: k-loop unrolled x2 (compile-time buffer parity),
// per-thread LDS read bases in registers with constant ds_read offsets,
// running global staging pointers (+= BK). Theory: VALUBusy=20% (~1200
// cyc/tile) was per-tile address recomputation sitting in the barrier-
// serialized read windows.

typedef unsigned short u16;
typedef short bf16x8 __attribute__((ext_vector_type(8)));   // 8 bf16 = 4 VGPRs
typedef float f32x4 __attribute__((ext_vector_type(4)));
typedef unsigned short ushort8 __attribute__((ext_vector_type(8)));

#define MDIM 4096
#define NDIM 4096
#define KD   4096
#define BM 256
#define BN 256
#define BK 64
#define NKT (KD / BK)          // 64 K-tiles
#define NTN (NDIM / BN)        // 16 column tiles
#define HT  (128 * 64)         // u16 elements per half-tile (16 KB)

__device__ __forceinline__ u16 f2bf(float f) {
  unsigned int u = __float_as_uint(f);
  u += 0x7fffu + ((u >> 16) & 1u);
  return (u16)(u >> 16);
}

__global__ void f32_to_bf16_kernel(const float* __restrict__ in,
                                   u16* __restrict__ out, int n8) {
  int i = blockIdx.x * blockDim.x + threadIdx.x;
  int stride = gridDim.x * blockDim.x;
  for (; i < n8; i += stride) {
    const float4* p = (const float4*)in + (size_t)i * 2;
    float4 a = p[0];
    float4 b = p[1];
    ushort8 o;
    o[0] = f2bf(a.x); o[1] = f2bf(a.y); o[2] = f2bf(a.z); o[3] = f2bf(a.w);
    o[4] = f2bf(b.x); o[5] = f2bf(b.y); o[6] = f2bf(b.z); o[7] = f2bf(b.w);
    ((ushort8*)out)[i] = o;
  }
}

__device__ __forceinline__ void gload_lds16(const u16* g, u16* l) {
  __builtin_amdgcn_global_load_lds(
      (__attribute__((address_space(1))) void*)(g),
      (__attribute__((address_space(3))) void*)(l), 16, 0, 0);
}

#define LDSOFF(buf, arr, half) ((((((buf) * 2) + (arr)) * 2) + (half)) * HT)

// Stage whole K-tile for buffer `c` (8 gload_lds/thread), advance gp by BK.
// gp mapping: q>>2 = A/B, (q>>1)&1 = half, q&1 = it (512-chunk group).
#define STAGE_TILE(c)                                                     \
  {                                                                       \
    _Pragma("unroll")                                                     \
    for (int q = 0; q < 8; ++q) {                                         \
      gload_lds16(gp[q], sm + LDSOFF((c), (q >> 2), ((q >> 1) & 1)) +     \
                             (q & 1) * 4096 + wdof);                      \
      gp[q] += BK;                                                        \
    }                                                                     \
  }

// One phase: 4 A-frag reads (+4 B-frag reads when LOADB), barrier,
// 16 MFMA under setprio, barrier. Reads use register base + const offset.
#define PHASE(c, mg, ks, LOADB)                                           \
  {                                                                       \
    bf16x8 afr[4];                                                        \
    _Pragma("unroll")                                                     \
    for (int mm = 0; mm < 4; ++mm)                                        \
      afr[mm] = *(const bf16x8*)(ARB[(c)][(ks)] + ((mg)*4 + mm) * 1024);  \
    if (LOADB) {                                                          \
      _Pragma("unroll")                                                   \
      for (int n = 0; n < 4; ++n)                                         \
        bfr[n] = *(const bf16x8*)(BRB[(c)][(ks)] + n * 1024);             \
    }                                                                     \
    __builtin_amdgcn_s_barrier();                                         \
    __builtin_amdgcn_s_setprio(1);                                        \
    _Pragma("unroll")                                                     \
    for (int mm = 0; mm < 4; ++mm)                                        \
      _Pragma("unroll")                                                   \
      for (int n = 0; n < 4; ++n)                                         \
        acc[(mg)*4 + mm][n] = __builtin_amdgcn_mfma_f32_16x16x32_bf16(    \
            afr[mm], bfr[n], acc[(mg)*4 + mm][n], 0, 0, 0);               \
    __builtin_amdgcn_s_setprio(0);                                        \
    __builtin_amdgcn_s_barrier();                                         \
  }

// One K-tile: stage next tile (counted vmcnt), validation barrier, 4 phases.
#define TILE(c, DO_STAGE)                                                 \
  {                                                                       \
    if (DO_STAGE) {                                                       \
      STAGE_TILE((c) ^ 1)                                                 \
      asm volatile("s_waitcnt vmcnt(8)" ::: "memory");                    \
    } else {                                                              \
      asm volatile("s_waitcnt vmcnt(0)" ::: "memory");                    \
    }                                                                     \
    __builtin_amdgcn_s_barrier();                                         \
    PHASE(c, 0, 0, true)                                                  \
    PHASE(c, 1, 0, false)                                                 \
    PHASE(c, 0, 1, true)                                                  \
    PHASE(c, 1, 1, false)                                                 \
  }

__global__ __launch_bounds__(512, 2) void gemm_gelu_max_kernel(
    const u16* __restrict__ A,    // x bf16 [4096][4096], K contiguous
    const u16* __restrict__ Bw,   // weight bf16 [4096][4096], K contiguous
    const float* __restrict__ bias,
    float* __restrict__ partials) {
  __shared__ __align__(16) u16 sm[2 * 2 * 2 * HT];  // 128 KiB
  __shared__ float pmx[8][128];                      // 4 KiB

  const int t = threadIdx.x;
  const int wave = t >> 6;
  const int lane = t & 63;
  const int warp_m = wave >> 2;        // A half
  const int warp_n = wave & 3;
  const int wn2 = warp_n >> 1;         // B half
  const int bn0 = (warp_n & 1) * 64;   // col base within B half
  const int l15 = lane & 15;
  const int l4 = lane >> 4;
  const int l7 = lane & 7;
  const int wdof = wave * 512;         // u16 elems: wave's gload_lds dest slot

  // T1: XCD-aware 2D swizzle (bid%8 -> XCD; XCD owns 4x8 tile region)
  const int bid = blockIdx.x;
  const int c8 = bid & 7;
  const int j = bid >> 3;
  const int tx = ((c8 & 3) << 2) + (j & 3);    // 0..15
  const int ty = ((c8 >> 2) << 3) + (j >> 2);  // 0..15
  const int brow = ty * BM;
  const int bcol = tx * BN;

  // per-thread swizzled 16B-chunk offsets (u16 elems) for k-slice 0/1
  const int cko0 = ((l4 ^ l7) << 3);
  const int cko1 = (((4 + l4) ^ l7) << 3);

  // LDS read base pointers per (buffer, ks); frag offsets become const imm
  const u16* ARB[2][2];
  const u16* BRB[2][2];
#pragma unroll
  for (int c = 0; c < 2; ++c) {
    ARB[c][0] = sm + LDSOFF(c, 0, warp_m) + l15 * 64 + cko0;
    ARB[c][1] = sm + LDSOFF(c, 0, warp_m) + l15 * 64 + cko1;
    BRB[c][0] = sm + LDSOFF(c, 1, wn2) + bn0 * 64 + l15 * 64 + cko0;
    BRB[c][1] = sm + LDSOFF(c, 1, wn2) + bn0 * 64 + l15 * 64 + cko1;
  }

  // running global staging pointers (pre-swizzled source, rule #21)
  const u16* gp[8];
#pragma unroll
  for (int it = 0; it < 2; ++it) {
    const int chunk = it * 512 + t;
    const int r = chunk >> 3;
    const int sw = ((chunk & 7) ^ (r & 7)) << 3;
    gp[0 + it] = A  + (size_t)(brow + r) * KD + sw;        // A half0
    gp[2 + it] = A  + (size_t)(brow + 128 + r) * KD + sw;  // A half1
    gp[4 + it] = Bw + (size_t)(bcol + r) * KD + sw;        // B half0
    gp[6 + it] = Bw + (size_t)(bcol + 128 + r) * KD + sw;  // B half1
  }

  f32x4 acc[8][4] = {};   // per-wave 128x64 output
  bf16x8 bfr[4];          // B frags, live across phase pairs

  // prologue: tile 0 -> buf 0
  STAGE_TILE(0)

  for (int kt2 = 0; kt2 < NKT / 2 - 1; ++kt2) {
    TILE(0, true)
    TILE(1, true)
  }
  TILE(0, true)    // tile 62 (stages tile 63 into buf1)
  TILE(1, false)   // tile 63

  // ---- epilogue: bias + 2*gelu_tanh, row-max over cols
  // C/D layout per 16x16 frag: col = l15, row = l4*4 + j
  float rmax_[8][4];
#pragma unroll
  for (int m = 0; m < 8; ++m)
#pragma unroll
    for (int j2 = 0; j2 < 4; ++j2) rmax_[m][j2] = -1e30f;

#pragma unroll
  for (int n = 0; n < 4; ++n) {
    const float bv = bias[bcol + warp_n * 64 + n * 16 + l15];
#pragma unroll
    for (int m = 0; m < 8; ++m) {
#pragma unroll
      for (int j2 = 0; j2 < 4; ++j2) {
        float x = acc[m][n][j2] + bv;
        float u = 0.7978845608f * x * (1.0f + 0.044715f * x * x);
        float e = exp2f(u * 2.8853900817779268f);   // 2*log2(e)
        float r = __builtin_amdgcn_rcpf(e + 1.0f);
        float g = 2.0f * x * (1.0f - r);
        rmax_[m][j2] = fmaxf(rmax_[m][j2], g);
      }
    }
  }

#pragma unroll
  for (int m = 0; m < 8; ++m) {
#pragma unroll
    for (int j2 = 0; j2 < 4; ++j2) {
      float v = rmax_[m][j2];
      v = fmaxf(v, __shfl_xor(v, 1, 64));
      v = fmaxf(v, __shfl_xor(v, 2, 64));
      v = fmaxf(v, __shfl_xor(v, 4, 64));
      v = fmaxf(v, __shfl_xor(v, 8, 64));
      if (l15 == 0) pmx[wave][m * 16 + l4 * 4 + j2] = v;
    }
  }
  __syncthreads();

  if (t < 256) {
    int gm = t >> 7;
    int r = t & 127;
    float v = fmaxf(fmaxf(pmx[gm * 4 + 0][r], pmx[gm * 4 + 1][r]),
                    fmaxf(pmx[gm * 4 + 2][r], pmx[gm * 4 + 3][r]));
    partials[(size_t)tx * MDIM + brow + t] = v;
  }
}

__global__ void rowmax_kernel(const float* __restrict__ partials,
                              float* __restrict__ out) {
  int r = blockIdx.x * blockDim.x + threadIdx.x;
  if (r < MDIM) {
    float m = -1e30f;
#pragma unroll
    for (int tt = 0; tt < NTN; ++tt) m = fmaxf(m, partials[(size_t)tt * MDIM + r]);
    out[r] = m;
  }
}

extern "C" void kernel_launch(void* const* d_in, const int* in_sizes, int n_in,
                              void* d_out, int out_size, void* d_ws, size_t ws_size,
                              hipStream_t stream) {
  const float* x = (const float*)d_in[0];
  const float* w = (const float*)d_in[1];
  const float* bias = (const float*)d_in[2];
  float* out = (float*)d_out;

  u16* xb = (u16*)d_ws;
  u16* wb = xb + (size_t)MDIM * KD;
  float* partials = (float*)(wb + (size_t)NDIM * KD);

  const int n8 = (MDIM * KD) / 8;
  f32_to_bf16_kernel<<<2048, 256, 0, stream>>>(x, xb, n8);
  f32_to_bf16_kernel<<<2048, 256, 0, stream>>>(w, wb, n8);

  gemm_gelu_max_kernel<<<dim3(256), 512, 0, stream>>>(xb, wb, bias, partials);

  rowmax_kernel<<<MDIM / 256, 256, 0, stream>>>(partials, out);
}

// Round 5
// 158.633 us; speedup vs baseline: 1.4443x; 1.0671x over previous
//
#include <hip/hip_runtime.h>
#include <hip/hip_bf16.h>
#include <math.h>

// out[b] = max_o( 2 * gelu_tanh( x[b,:] . weight[o,:] + bias[o] ) )
// 4096 x 4096 x 4096, fp32 in, fp32 out[4096].
//
// Round 5: overlap LDS reads with MFMA. Round-4 model: MFMA pipe 2480 cyc +
// LDS pipe 2300 cyc per K-tile, serialized by the read->barrier->MFMA phase
// structure => 5600 cyc/tile. New phase: MFMA(frags read last phase) ->
// [stage @p0] -> ds_read next phase's frags -> barrier. Frag regs double-
// buffered (afP/afQ, bf0/bf1), all indices static. Tile boundary: phase 3
// does vmcnt(0)+barrier then prefetches next tile's p0 frags from the
// freshly validated buffer. 4 barriers/tile (was 9).

typedef unsigned short u16;
typedef short bf16x8 __attribute__((ext_vector_type(8)));   // 8 bf16 = 4 VGPRs
typedef float f32x4 __attribute__((ext_vector_type(4)));
typedef unsigned short ushort8 __attribute__((ext_vector_type(8)));

#define MDIM 4096
#define NDIM 4096
#define KD   4096
#define BM 256
#define BN 256
#define BK 64
#define NKT (KD / BK)          // 64 K-tiles
#define NTN (NDIM / BN)        // 16 column tiles
#define HT  (128 * 64)         // u16 elements per half-tile (16 KB)

__device__ __forceinline__ u16 f2bf(float f) {
  unsigned int u = __float_as_uint(f);
  u += 0x7fffu + ((u >> 16) & 1u);
  return (u16)(u >> 16);
}

__global__ void f32_to_bf16_kernel(const float* __restrict__ in,
                                   u16* __restrict__ out, int n8) {
  int i = blockIdx.x * blockDim.x + threadIdx.x;
  int stride = gridDim.x * blockDim.x;
  for (; i < n8; i += stride) {
    const float4* p = (const float4*)in + (size_t)i * 2;
    float4 a = p[0];
    float4 b = p[1];
    ushort8 o;
    o[0] = f2bf(a.x); o[1] = f2bf(a.y); o[2] = f2bf(a.z); o[3] = f2bf(a.w);
    o[4] = f2bf(b.x); o[5] = f2bf(b.y); o[6] = f2bf(b.z); o[7] = f2bf(b.w);
    ((ushort8*)out)[i] = o;
  }
}

__device__ __forceinline__ void gload_lds16(const u16* g, u16* l) {
  __builtin_amdgcn_global_load_lds(
      (__attribute__((address_space(1))) void*)(g),
      (__attribute__((address_space(3))) void*)(l), 16, 0, 0);
}

#define LDSOFF(buf, arr, half) ((((((buf) * 2) + (arr)) * 2) + (half)) * HT)

// Stage whole next K-tile into buffer `c` (8 gload_lds/thread), bump gp.
#define STAGE_TILE(c)                                                     \
  {                                                                       \
    _Pragma("unroll")                                                     \
    for (int q = 0; q < 8; ++q) {                                         \
      gload_lds16(gp[q], sm + LDSOFF((c), (q >> 2), ((q >> 1) & 1)) +     \
                             (q & 1) * 4096 + wdof);                      \
      gp[q] += BK;                                                        \
    }                                                                     \
  }

#define READ_A(dst, c, ks, mg)                                            \
  {                                                                       \
    _Pragma("unroll")                                                     \
    for (int mm = 0; mm < 4; ++mm)                                        \
      dst[mm] = *(const bf16x8*)(ARB[(c)][(ks)] + ((mg)*4 + mm) * 1024);  \
  }

#define READ_B(dst, c, ks)                                                \
  {                                                                       \
    _Pragma("unroll")                                                     \
    for (int n = 0; n < 4; ++n)                                           \
      dst[n] = *(const bf16x8*)(BRB[(c)][(ks)] + n * 1024);               \
  }

#define MFMA16(af, bfv, mg)                                               \
  {                                                                       \
    __builtin_amdgcn_s_setprio(1);                                        \
    _Pragma("unroll")                                                     \
    for (int mm = 0; mm < 4; ++mm)                                        \
      _Pragma("unroll")                                                   \
      for (int n = 0; n < 4; ++n)                                         \
        acc[(mg)*4 + mm][n] = __builtin_amdgcn_mfma_f32_16x16x32_bf16(    \
            af[mm], bfv[n], acc[(mg)*4 + mm][n], 0, 0, 0);                \
    __builtin_amdgcn_s_setprio(0);                                        \
  }

// One K-tile, compute buffer c. Frag rotation (all static):
//  p0: MFMA(afP,bf0,mg0); stage->c^1;            read afQ <- (c,ks0,mg1)
//  p1: MFMA(afQ,bf0,mg1); read afP <- (c,ks1,mg0); bf1 <- (c,ks1)
//  p2: MFMA(afP,bf1,mg0); read afQ <- (c,ks1,mg1)
//  p3: MFMA(afQ,bf1,mg1); vmcnt(0); barrier; read afP,bf0 <- (c^1,ks0,mg0)
#define TILE(c, DO_STAGE, LAST)                                           \
  {                                                                       \
    MFMA16(afP, bf0, 0)                                                   \
    if (DO_STAGE) { STAGE_TILE((c) ^ 1) }                                 \
    READ_A(afQ, c, 0, 1)                                                  \
    __builtin_amdgcn_s_barrier();                                         \
    MFMA16(afQ, bf0, 1)                                                   \
    READ_A(afP, c, 1, 0)                                                  \
    READ_B(bf1, c, 1)                                                     \
    __builtin_amdgcn_s_barrier();                                         \
    MFMA16(afP, bf1, 0)                                                   \
    READ_A(afQ, c, 1, 1)                                                  \
    __builtin_amdgcn_s_barrier();                                         \
    MFMA16(afQ, bf1, 1)                                                   \
    if (!LAST) {                                                          \
      asm volatile("s_waitcnt vmcnt(0)" ::: "memory");                    \
      __builtin_amdgcn_s_barrier();                                       \
      READ_A(afP, (c) ^ 1, 0, 0)                                          \
      READ_B(bf0, (c) ^ 1, 0)                                             \
    }                                                                     \
  }

__global__ __launch_bounds__(512, 2) void gemm_gelu_max_kernel(
    const u16* __restrict__ A,    // x bf16 [4096][4096], K contiguous
    const u16* __restrict__ Bw,   // weight bf16 [4096][4096], K contiguous
    const float* __restrict__ bias,
    float* __restrict__ partials) {
  __shared__ __align__(16) u16 sm[2 * 2 * 2 * HT];  // 128 KiB
  __shared__ float pmx[8][128];                      // 4 KiB

  const int t = threadIdx.x;
  const int wave = t >> 6;
  const int lane = t & 63;
  const int warp_m = wave >> 2;        // A half
  const int warp_n = wave & 3;
  const int wn2 = warp_n >> 1;         // B half
  const int bn0 = (warp_n & 1) * 64;   // col base within B half
  const int l15 = lane & 15;
  const int l4 = lane >> 4;
  const int l7 = lane & 7;
  const int wdof = wave * 512;         // wave's gload_lds dest slot (u16)

  // T1: XCD-aware 2D swizzle (bid%8 -> XCD; XCD owns 4x8 tile region)
  const int bid = blockIdx.x;
  const int c8 = bid & 7;
  const int j = bid >> 3;
  const int tx = ((c8 & 3) << 2) + (j & 3);    // 0..15
  const int ty = ((c8 >> 2) << 3) + (j >> 2);  // 0..15
  const int brow = ty * BM;
  const int bcol = tx * BN;

  // per-thread swizzled 16B-chunk offsets (u16 elems) for k-slice 0/1
  const int cko0 = ((l4 ^ l7) << 3);
  const int cko1 = (((4 + l4) ^ l7) << 3);

  // LDS read base pointers per (buffer, ks); frag offsets are const imm
  const u16* ARB[2][2];
  const u16* BRB[2][2];
#pragma unroll
  for (int c = 0; c < 2; ++c) {
    ARB[c][0] = sm + LDSOFF(c, 0, warp_m) + l15 * 64 + cko0;
    ARB[c][1] = sm + LDSOFF(c, 0, warp_m) + l15 * 64 + cko1;
    BRB[c][0] = sm + LDSOFF(c, 1, wn2) + bn0 * 64 + l15 * 64 + cko0;
    BRB[c][1] = sm + LDSOFF(c, 1, wn2) + bn0 * 64 + l15 * 64 + cko1;
  }

  // running global staging pointers (pre-swizzled source, rule #21)
  const u16* gp[8];
#pragma unroll
  for (int it = 0; it < 2; ++it) {
    const int chunk = it * 512 + t;
    const int r = chunk >> 3;
    const int sw = ((chunk & 7) ^ (r & 7)) << 3;
    gp[0 + it] = A  + (size_t)(brow + r) * KD + sw;        // A half0
    gp[2 + it] = A  + (size_t)(brow + 128 + r) * KD + sw;  // A half1
    gp[4 + it] = Bw + (size_t)(bcol + r) * KD + sw;        // B half0
    gp[6 + it] = Bw + (size_t)(bcol + 128 + r) * KD + sw;  // B half1
  }

  f32x4 acc[8][4] = {};   // per-wave 128x64 output
  bf16x8 afP[4], afQ[4], bf0[4], bf1[4];

  // prologue: tile 0 -> buf 0; preload p0 frags
  STAGE_TILE(0)
  asm volatile("s_waitcnt vmcnt(0)" ::: "memory");
  __builtin_amdgcn_s_barrier();
  READ_A(afP, 0, 0, 0)
  READ_B(bf0, 0, 0)

  for (int kt2 = 0; kt2 < NKT / 2 - 1; ++kt2) {
    TILE(0, true, false)
    TILE(1, true, false)
  }
  TILE(0, true, false)    // tile 62 (stages tile 63 into buf1)
  TILE(1, false, true)    // tile 63

  // ---- epilogue: bias + 2*gelu_tanh, row-max over cols
  // C/D layout per 16x16 frag: col = l15, row = l4*4 + j
  float rmax_[8][4];
#pragma unroll
  for (int m = 0; m < 8; ++m)
#pragma unroll
    for (int j2 = 0; j2 < 4; ++j2) rmax_[m][j2] = -1e30f;

#pragma unroll
  for (int n = 0; n < 4; ++n) {
    const float bv = bias[bcol + warp_n * 64 + n * 16 + l15];
#pragma unroll
    for (int m = 0; m < 8; ++m) {
#pragma unroll
      for (int j2 = 0; j2 < 4; ++j2) {
        float x = acc[m][n][j2] + bv;
        float u = 0.7978845608f * x * (1.0f + 0.044715f * x * x);
        float e = exp2f(u * 2.8853900817779268f);   // 2*log2(e)
        float r = __builtin_amdgcn_rcpf(e + 1.0f);
        float g = 2.0f * x * (1.0f - r);
        rmax_[m][j2] = fmaxf(rmax_[m][j2], g);
      }
    }
  }

#pragma unroll
  for (int m = 0; m < 8; ++m) {
#pragma unroll
    for (int j2 = 0; j2 < 4; ++j2) {
      float v = rmax_[m][j2];
      v = fmaxf(v, __shfl_xor(v, 1, 64));
      v = fmaxf(v, __shfl_xor(v, 2, 64));
      v = fmaxf(v, __shfl_xor(v, 4, 64));
      v = fmaxf(v, __shfl_xor(v, 8, 64));
      if (l15 == 0) pmx[wave][m * 16 + l4 * 4 + j2] = v;
    }
  }
  __syncthreads();

  if (t < 256) {
    int gm = t >> 7;
    int r = t & 127;
    float v = fmaxf(fmaxf(pmx[gm * 4 + 0][r], pmx[gm * 4 + 1][r]),
                    fmaxf(pmx[gm * 4 + 2][r], pmx[gm * 4 + 3][r]));
    partials[(size_t)tx * MDIM + brow + t] = v;
  }
}

__global__ void rowmax_kernel(const float* __restrict__ partials,
                              float* __restrict__ out) {
  int r = blockIdx.x * blockDim.x + threadIdx.x;
  if (r < MDIM) {
    float m = -1e30f;
#pragma unroll
    for (int tt = 0; tt < NTN; ++tt) m = fmaxf(m, partials[(size_t)tt * MDIM + r]);
    out[r] = m;
  }
}

extern "C" void kernel_launch(void* const* d_in, const int* in_sizes, int n_in,
                              void* d_out, int out_size, void* d_ws, size_t ws_size,
                              hipStream_t stream) {
  const float* x = (const float*)d_in[0];
  const float* w = (const float*)d_in[1];
  const float* bias = (const float*)d_in[2];
  float* out = (float*)d_out;

  u16* xb = (u16*)d_ws;
  u16* wb = xb + (size_t)MDIM * KD;
  float* partials = (float*)(wb + (size_t)NDIM * KD);

  const int n8 = (MDIM * KD) / 8;
  f32_to_bf16_kernel<<<2048, 256, 0, stream>>>(x, xb, n8);
  f32_to_bf16_kernel<<<2048, 256, 0, stream>>>(w, wb, n8);

  gemm_gelu_max_kernel<<<dim3(256), 512, 0, stream>>>(xb, wb, bias, partials);

  rowmax_kernel<<<MDIM / 256, 256, 0, stream>>>(partials, out);
}